// Round 7
// baseline (1193.958 us; speedup 1.0000x reference)
//
#include <hip/hip_runtime.h>
#include <stdint.h>

typedef unsigned short ushort_t;
typedef unsigned int uint_t;

#define H_SZ   1024
#define D_OUT  512
#define MAXN   64
#define MIDSP  512
#define MIDCD  512
#define MIDDEC 768

typedef __bf16 bf16x8 __attribute__((ext_vector_type(8)));
typedef float  f32x4  __attribute__((ext_vector_type(4)));

static __device__ __forceinline__ float asf(uint_t u) { union { uint_t i; float f; } c; c.i = u; return c.f; }
static __device__ __forceinline__ uint_t rnbf(float f) {            // fp32 -> bf16 (RNE), low 16 bits
  union { uint_t i; float f; } c; c.f = f;
  return (c.i + 0x7fffu + ((c.i >> 16) & 1u)) >> 16;
}
static __device__ __forceinline__ ushort_t f2bf(float f) { return (ushort_t)rnbf(f); }
static __device__ __forceinline__ uint_t mul2bf(uint_t a, uint_t b) {  // 2x packed bf16 multiply
  float a0 = asf(a << 16), a1 = asf(a & 0xffff0000u);
  float b0 = asf(b << 16), b1 = asf(b & 0xffff0000u);
  return rnbf(a0 * b0) | (rnbf(a1 * b1) << 16);
}
static __device__ __forceinline__ double mish_d(double x) { return x * tanh(log1p(exp(x))); }
static __device__ __forceinline__ float mish_f(float x) {
  // mish(x) = x*(t^2+2t)/(t^2+2t+2), t=e^x  (algebraic tanh(softplus))
  float t = __expf(x);
  float u = t * t + 2.f * t;
  float r = u / (u + 2.f);
  return (x > 30.f) ? x : x * r;
}

// ---------------- transpose + fp32->bf16 convert (dims multiples of 32) ----------------
__global__ __launch_bounds__(256) void k_transpose_cvt(const float* __restrict__ src,
                                                       ushort_t* __restrict__ dst, int R, int C) {
  __shared__ float tile[32][33];
  const int c0 = blockIdx.x * 32, r0 = blockIdx.y * 32;
  const int tc = threadIdx.x & 31, tr = threadIdx.x >> 5;
#pragma unroll
  for (int i = 0; i < 4; ++i) {
    const int r = tr + i * 8;
    tile[r][tc] = src[(size_t)(r0 + r) * C + (c0 + tc)];
  }
  __syncthreads();
#pragma unroll
  for (int i = 0; i < 4; ++i) {
    const int rr = tr + i * 8;
    dst[(size_t)(c0 + rr) * R + (r0 + tc)] = f2bf(tile[tc][rr]);
  }
}

// ---------------- key table fp32 -> bf16 ----------------
__global__ __launch_bounds__(256) void k_cvtkey(const float* __restrict__ src, ushort_t* __restrict__ dst) {
  const int i = blockIdx.x * 1024 + threadIdx.x;
#pragma unroll
  for (int j = 0; j < 4; ++j) dst[i + j * 256] = f2bf(src[i + j * 256]);
}

// ---------------- enc table: enc[v] = mish(v*cd_w1+cd_b1) @ cd_w2 + cd_b2 ----------------
// grid (65, 4): blockIdx.y picks a 256-col quarter. Per-column accumulation order unchanged.
__global__ __launch_bounds__(256) void k_enc(const float* __restrict__ w1, const float* __restrict__ b1,
                                             const float* __restrict__ w2, const float* __restrict__ b2,
                                             float* __restrict__ enc) {
  const int v = blockIdx.x, t = threadIdx.x;
  const int c = blockIdx.y * 256 + t;
  __shared__ float m[MIDCD];
  for (int i = t; i < MIDCD; i += 256) {
    double a = (double)v * (double)w1[i] + (double)b1[i];
    m[i] = (float)mish_d(a);
  }
  __syncthreads();
  double s = (double)b2[c];
  for (int k = 0; k < MIDCD; ++k) s += (double)m[k] * (double)w2[(size_t)k * H_SZ + c];
  enc[(size_t)v * H_SZ + c] = (float)s;
}

// ---------------- n-path: 4 rows per block (grid 512 -> 2 blocks/CU for TLP) ----------------
// fp32 S accumulation, fp64 LN/mish/dot. Per-row numerics identical to the 8-row version.
__global__ __launch_bounds__(256) void k_npath(
    const float* __restrict__ z, const float* __restrict__ w1, const float* __restrict__ b1,
    const float* __restrict__ g, const float* __restrict__ be,
    const float* __restrict__ w2, const float* __restrict__ b2,
    const float* __restrict__ enc, int* __restrict__ nbuf,
    ushort_t* __restrict__ zc, float* __restrict__ outb) {
  const int t = threadIdx.x;
  const int r0 = blockIdx.x * 4;
  const int lane = t & 63, wv = t >> 6;
  __shared__ float zs[4][H_SZ];      // 16 KB
  __shared__ double wred[4];
  __shared__ int n4[4];

#pragma unroll
  for (int i = 0; i < 16; ++i) {
    const int idx = i * 256 + t;
    zs[idx >> 10][idx & 1023] = z[(size_t)r0 * H_SZ + idx];
  }
  __syncthreads();

  const int c0 = t, c1 = t + 256;
  float a0[4], a1[4];
#pragma unroll
  for (int r = 0; r < 4; ++r) { a0[r] = 0.f; a1[r] = 0.f; }

  for (int k = 0; k < H_SZ; k += 4) {
    float4 zr[4];
#pragma unroll
    for (int r = 0; r < 4; ++r) zr[r] = *(const float4*)&zs[r][k];
#pragma unroll
    for (int kk = 0; kk < 4; ++kk) {
      const float w0 = w1[(size_t)(k + kk) * MIDSP + c0];
      const float w1v = w1[(size_t)(k + kk) * MIDSP + c1];
#pragma unroll
      for (int r = 0; r < 4; ++r) {
        const float zk = ((const float*)&zr[r])[kk];
        a0[r] += zk * w0;
        a1[r] += zk * w1v;
      }
    }
  }

  auto block_sum = [&](double v) -> double {
#pragma unroll
    for (int off = 32; off > 0; off >>= 1) v += __shfl_down(v, off, 64);
    if (lane == 0) wred[wv] = v;
    __syncthreads();
    const double s = wred[0] + wred[1] + wred[2] + wred[3];
    __syncthreads();
    return s;
  };

  const double bia0 = (double)b1[c0], bia1 = (double)b1[c1];
  const double g0 = (double)g[c0], g1 = (double)g[c1];
  const double be0 = (double)be[c0], be1 = (double)be[c1];
  const double wv0 = (double)w2[c0], wv1 = (double)w2[c1];
  const double b2v = (double)b2[0];

  for (int r = 0; r < 4; ++r) {
    const double x0 = (double)a0[r] + bia0;
    const double x1 = (double)a1[r] + bia1;
    const double mu = block_sum(x0 + x1) * (1.0 / 512.0);
    const double varr = block_sum((x0 - mu) * (x0 - mu) + (x1 - mu) * (x1 - mu)) * (1.0 / 512.0);
    const double rs = 1.0 / sqrt(varr + 1e-5);
    const double h0 = mish_d((x0 - mu) * rs * g0 + be0);
    const double h1 = mish_d((x1 - mu) * rs * g1 + be1);
    const double logit = block_sum(h0 * wv0 + h1 * wv1) + b2v;
    if (t == 0) n4[r] = (int)fmin(64.0, fmax(0.0, rint(logit)));  // rint = half-to-even = np.round
  }
  __syncthreads();

  if (t < 4) nbuf[r0 + t] = n4[t];
  {
    const int r = t >> 6, j = t & 63;    // 256 = 4 rows x 64 cols
    outb[(size_t)(r0 + r) * MAXN + j] = (j < n4[r]) ? (float)(r0 + r) : -1.0f;
  }
#pragma unroll
  for (int i = 0; i < 16; ++i) {
    const int idx = i * 256 + t;
    const int r = idx >> 10, c = idx & 1023;
    zc[(size_t)(r0 + r) * H_SZ + c] = f2bf(zs[r][c] - enc[(size_t)n4[r] * H_SZ + c]);
  }
}

// ---------------- fused decoder v8: 32-row sA (64K) + 16K sT = 80 KiB/block --------------
// R6 post-mortem: v7 failed opaquely (no timing block -> container-level, likely infra;
// the only compile-regime delta vs the WORKING v6 was launch_bounds(512,4)). v8 = v7 with
// launch_bounds(512,2), the proven regime. KEY FACT: launch_bounds only CAPS registers;
// residency comes from actual usage. v6's natural VGPR was 100 <= 128, which already
// permits 4 waves/SIMD (16 waves/CU = 2 blocks x 8 waves). So the LDS cut to 80 KiB
// (2 x 80 = 160 KiB) alone yields 2 blocks/CU -- no forced register cap, no spill risk.
// If exact-fit co-residency fails we merely keep v6 perf + halved A-gen (no regression).
// n~32 for every b -> 1 sweep (MT<=2) is the universal path; rare JT=3/4 runs 2 sweeps.
template <int MT>
static __device__ __forceinline__ void dec_sweep(
    char* sA, char* sT,
    const ushort_t* __restrict__ w1t, const float* __restrict__ db1,
    const ushort_t* __restrict__ w2t, const float* __restrict__ db2,
    float* __restrict__ ob, const int tid, const int lim) {  // ob -> row r0 of this b
  const int lane = tid & 63;
  const int w = tid >> 6;           // 8 waves
  const int q = lane >> 4;
  const int l15 = lane & 15;

  f32x4 z4 = {0.f, 0.f, 0.f, 0.f};
  f32x4 acc2[MT][4];                // X accumulator, persists across passes
#pragma unroll
  for (int mt = 0; mt < MT; ++mt)
#pragma unroll
    for (int i = 0; i < 4; ++i) acc2[mt][i] = z4;

  for (int p = 0; p < 3; ++p) {
    // ---- GEMM1 slab: T[:, p*256 .. p*256+256), barrier-free, branch-free over K=1024 ----
    f32x4 acc[MT][2];
#pragma unroll
    for (int mt = 0; mt < MT; ++mt)
#pragma unroll
      for (int i = 0; i < 2; ++i) acc[mt][i] = z4;

    const ushort_t* bp1[2];
#pragma unroll
    for (int i = 0; i < 2; ++i)
      bp1[i] = w1t + (size_t)(p * 256 + (w * 2 + i) * 16 + l15) * H_SZ + q * 8;

#pragma unroll 8
    for (int ks = 0; ks < 32; ++ks) {      // k-offset = ks*32, same order as v2/v5/v6
      bf16x8 bfr0 = *(const bf16x8*)(bp1[0] + ks * 32);
      bf16x8 bfr1 = *(const bf16x8*)(bp1[1] + ks * 32);
      bf16x8 afr[MT];
#pragma unroll
      for (int mt = 0; mt < MT; ++mt)
        afr[mt] = *(const bf16x8*)(sA + (mt * 16 + l15) * 2048 + (((ks * 4 + q) ^ (l15 & 7)) * 16));
#pragma unroll
      for (int mt = 0; mt < MT; ++mt) {
        acc[mt][0] = __builtin_amdgcn_mfma_f32_16x16x32_bf16(afr[mt], bfr0, acc[mt][0], 0, 0, 0);
        acc[mt][1] = __builtin_amdgcn_mfma_f32_16x16x32_bf16(afr[mt], bfr1, acc[mt][1], 0, 0, 0);
      }
    }

    // ---- epilogue1: +bias, mish, bf16 -> sT (XOR-swizzled 16B chunks), 32 rows ----
#pragma unroll
    for (int mt = 0; mt < MT; ++mt)
#pragma unroll
      for (int i = 0; i < 2; ++i) {
        const int pl = (w * 2 + i) * 16 + l15;       // local col 0..255
        const float bias = db1[p * 256 + pl];
        const int c = pl >> 3;
        const int off = (pl & 7) * 2;
#pragma unroll
        for (int r = 0; r < 4; ++r) {
          const int j = mt * 16 + q * 4 + r;
          *(ushort_t*)(sT + j * 512 + ((c ^ (j & 7)) * 16 + off)) = f2bf(mish_f(acc[mt][i][r] + bias));
        }
      }
    __syncthreads();

    // ---- GEMM2 partial: acc2 += T-slab @ W2[k-slab, :] ----
    const ushort_t* bp2[4];
#pragma unroll
    for (int i = 0; i < 4; ++i)
      bp2[i] = w2t + (size_t)((w * 4 + i) * 16 + l15) * MIDDEC + p * 256 + q * 8;

#pragma unroll
    for (int ksl = 0; ksl < 8; ++ksl) {
      bf16x8 bfr[4];
#pragma unroll
      for (int i = 0; i < 4; ++i) bfr[i] = *(const bf16x8*)(bp2[i] + ksl * 32);
      bf16x8 afr2[MT];
#pragma unroll
      for (int mt = 0; mt < MT; ++mt) {
        const int j = mt * 16 + l15;
        const int c = ksl * 4 + q;
        afr2[mt] = *(const bf16x8*)(sT + j * 512 + ((c ^ (j & 7)) * 16));
      }
#pragma unroll
      for (int mt = 0; mt < MT; ++mt)
#pragma unroll
        for (int i = 0; i < 4; ++i)
          acc2[mt][i] = __builtin_amdgcn_mfma_f32_16x16x32_bf16(afr2[mt], bfr[i], acc2[mt][i], 0, 0, 0);
    }
    __syncthreads();   // sT reads done before next pass's epilogue overwrites
  }

  // ---- X epilogue + store: 2 col-halves h, 32x256 staged in sT ----
  for (int h = 0; h < 2; ++h) {
    if ((w >> 2) == h) {             // waves owning cols [h*256, h*256+256)
#pragma unroll
      for (int mt = 0; mt < MT; ++mt)
#pragma unroll
        for (int i = 0; i < 4; ++i) {
          const int col = (w * 4 + i) * 16 + l15;    // global col
          const int cl = col & 255;
          const float bias = db2[col];
#pragma unroll
          for (int r = 0; r < 4; ++r) {
            const int j = mt * 16 + q * 4 + r;
            *(ushort_t*)(sT + j * 512 + cl * 2) = f2bf(acc2[mt][i][r] + bias);
          }
        }
    }
    __syncthreads();
    float* oh = ob + h * 256;
#pragma unroll
    for (int it = 0; it < 2; ++it) {
      const int e = it * 4096 + tid * 8;   // 0..8191 within 32x256 quarter
      const int row = e >> 8, cl = e & 255;
      float4 v0 = make_float4(0.f, 0.f, 0.f, 0.f);
      float4 v1 = make_float4(0.f, 0.f, 0.f, 0.f);
      if (row < lim) {
        const uint4 u = *(const uint4*)(sT + row * 512 + cl * 2);
        v0.x = asf(u.x << 16); v0.y = asf(u.x & 0xffff0000u);
        v0.z = asf(u.y << 16); v0.w = asf(u.y & 0xffff0000u);
        v1.x = asf(u.z << 16); v1.y = asf(u.z & 0xffff0000u);
        v1.z = asf(u.w << 16); v1.w = asf(u.w & 0xffff0000u);
      }
      *(float4*)(oh + (size_t)row * D_OUT + cl) = v0;
      *(float4*)(oh + (size_t)row * D_OUT + cl + 4) = v1;
    }
    __syncthreads();   // store reads done before next stage overwrites sT
  }
}

__global__ __launch_bounds__(512, 2) void k_dec(
    const ushort_t* __restrict__ key, const ushort_t* __restrict__ w1t,
    const float* __restrict__ db1, const ushort_t* __restrict__ w2t,
    const float* __restrict__ db2, const ushort_t* __restrict__ zc,
    const int* __restrict__ nbuf, float* __restrict__ out) {
  __shared__ char sA[65536];       // 32 rows x 1024 K bf16, row stride 2048B, XOR-16B-chunk swizzle
  __shared__ char sT[16384];       // 32 rows x 256 cols bf16, row stride 512B, XOR swizzle

  const int tid = threadIdx.x;
  const int b = blockIdx.x;

  int n = nbuf[b];
  n = n < 0 ? 0 : (n > MAXN ? MAXN : n);   // defensive clamp
  float* ob = out + (size_t)b * (MAXN * D_OUT);

  if (n == 0) {                     // dead b: zero-fill 64x512 fp32 and exit (uniform)
    const float4 z4f = make_float4(0.f, 0.f, 0.f, 0.f);
#pragma unroll
    for (int i = 0; i < 16; ++i) *(float4*)(ob + i * 2048 + tid * 4) = z4f;
    return;
  }
  const int JT = (n + 15) >> 4;     // live 16-row M-tiles (1..4), block-uniform
  const int nsweep = (JT + 1) >> 1; // 32-row sweeps (1 or 2)

  // ---- A-gen indexing: row gj = tid>>4 (0..31), 8 x 16B chunks per thread ----
  const int gj = tid >> 4;
  const int gk = tid & 15;
  const ushort_t* zrow = zc + (size_t)b * H_SZ + gk * 8;
  char* awbase = sA + gj * 2048;
  const int xj = gj & 7;

  for (int sw = 0; sw < nsweep; ++sw) {
    const int r0 = sw * 32;
    // A generation for rows [r0, r0+32): A[j][k] = zc[b][k] * key[r0+j][k]
    const ushort_t* keyrow = key + (size_t)(r0 + gj) * H_SZ + gk * 8;
#pragma unroll
    for (int i = 0; i < 8; ++i) {
      const int c = i * 16 + gk;    // chunk index 0..127 (XOR touches low 3 bits only)
      uint4 kv = *(const uint4*)(keyrow + i * 128);
      uint4 zv = *(const uint4*)(zrow + i * 128);
      uint4 r;
      r.x = mul2bf(kv.x, zv.x); r.y = mul2bf(kv.y, zv.y);
      r.z = mul2bf(kv.z, zv.z); r.w = mul2bf(kv.w, zv.w);
      *(uint4*)(awbase + ((c ^ xj) * 16)) = r;
    }
    __syncthreads();

    const int mt_live = JT - sw * 2;               // tiles in this sweep (1..2)
    const int lim0 = n - r0;
    const int lim = lim0 > 32 ? 32 : lim0;         // live rows in this sweep: 1..32
    if (mt_live >= 2) dec_sweep<2>(sA, sT, w1t, db1, w2t, db2, ob + (size_t)r0 * D_OUT, tid, lim);
    else              dec_sweep<1>(sA, sT, w1t, db1, w2t, db2, ob + (size_t)r0 * D_OUT, tid, lim);
    // dec_sweep ends with __syncthreads(); all sA reads complete before earlier barriers,
    // so next sweep's A-gen overwrite is safe.
  }

  if (nsweep == 1) {                // rows 32..63 dead for this b: zero-fill 32x512 fp32
    float* oz = ob + 32 * D_OUT;
    const float4 z4f = make_float4(0.f, 0.f, 0.f, 0.f);
#pragma unroll
    for (int i = 0; i < 8; ++i) *(float4*)(oz + i * 2048 + tid * 4) = z4f;
  }
}

// ---------------- launcher ----------------
extern "C" void kernel_launch(void* const* d_in, const int* in_sizes, int n_in,
                              void* d_out, int out_size, void* d_ws, size_t ws_size,
                              hipStream_t stream) {
  const float* z      = (const float*)d_in[0];
  const float* key    = (const float*)d_in[1];
  const float* sp_w1  = (const float*)d_in[2];
  const float* sp_b1  = (const float*)d_in[3];
  const float* sp_g   = (const float*)d_in[4];
  const float* sp_be  = (const float*)d_in[5];
  const float* sp_w2  = (const float*)d_in[6];
  const float* sp_b2  = (const float*)d_in[7];
  const float* cd_w1  = (const float*)d_in[8];
  const float* cd_b1  = (const float*)d_in[9];
  const float* cd_w2  = (const float*)d_in[10];
  const float* cd_b2  = (const float*)d_in[11];
  const float* dec_w1 = (const float*)d_in[12];
  const float* dec_b1 = (const float*)d_in[13];
  const float* dec_w2 = (const float*)d_in[14];
  const float* dec_b2 = (const float*)d_in[15];

  char* ws = (char*)d_ws;
  float*    enc   = (float*)(ws + 0);           // 65*1024*4   = 266,240
  int*      nbuf  = (int*)(ws + 266240);        // 2048*4      = 8,192
  ushort_t* zc    = (ushort_t*)(ws + 274432);   // 2048*1024*2 = 4,194,304
  ushort_t* w1t   = (ushort_t*)(ws + 4468736);  // 768*1024*2  = 1,572,864
  ushort_t* w2t   = (ushort_t*)(ws + 6041600);  // 512*768*2   = 786,432
  ushort_t* keyb  = (ushort_t*)(ws + 6828032);  // 64*1024*2   = 131,072

  float* out  = (float*)d_out;                           // x: 2048*64*512 fp32
  float* outb = out + (size_t)2048 * MAXN * D_OUT;       // batch: 2048*64 fp32

  (void)in_sizes; (void)n_in; (void)out_size; (void)ws_size;

  k_transpose_cvt<<<dim3(768 / 32, 1024 / 32), 256, 0, stream>>>(dec_w1, w1t, 1024, 768);
  k_transpose_cvt<<<dim3(512 / 32, 768 / 32), 256, 0, stream>>>(dec_w2, w2t, 768, 512);
  k_cvtkey<<<64, 256, 0, stream>>>(key, keyb);
  k_enc<<<dim3(65, 4), 256, 0, stream>>>(cd_w1, cd_b1, cd_w2, cd_b2, enc);
  k_npath<<<512, 256, 0, stream>>>(z, sp_w1, sp_b1, sp_g, sp_be, sp_w2, sp_b2, enc, nbuf, zc, outb);
  k_dec<<<2048, 512, 0, stream>>>(keyb, w1t, dec_b1, w2t, dec_b2, zc, nbuf, out);
}

// Round 8
// 1077.119 us; speedup vs baseline: 1.1085x; 1.1085x over previous
//
#include <hip/hip_runtime.h>
#include <stdint.h>

typedef unsigned short ushort_t;
typedef unsigned int uint_t;

#define H_SZ   1024
#define D_OUT  512
#define MAXN   64
#define MIDSP  512
#define MIDCD  512
#define MIDDEC 768

typedef __bf16 bf16x8 __attribute__((ext_vector_type(8)));
typedef float  f32x4  __attribute__((ext_vector_type(4)));

static __device__ __forceinline__ float asf(uint_t u) { union { uint_t i; float f; } c; c.i = u; return c.f; }
static __device__ __forceinline__ uint_t rnbf(float f) {            // fp32 -> bf16 (RNE), low 16 bits
  union { uint_t i; float f; } c; c.f = f;
  return (c.i + 0x7fffu + ((c.i >> 16) & 1u)) >> 16;
}
static __device__ __forceinline__ ushort_t f2bf(float f) { return (ushort_t)rnbf(f); }
static __device__ __forceinline__ float bf2f(float f) { return asf(rnbf(f) << 16); }  // round to bf16, keep fp32
static __device__ __forceinline__ uint_t mul2bf(uint_t a, uint_t b) {  // 2x packed bf16 multiply
  float a0 = asf(a << 16), a1 = asf(a & 0xffff0000u);
  float b0 = asf(b << 16), b1 = asf(b & 0xffff0000u);
  return rnbf(a0 * b0) | (rnbf(a1 * b1) << 16);
}
static __device__ __forceinline__ double mish_d(double x) { return x * tanh(log1p(exp(x))); }
static __device__ __forceinline__ float mish_f(float x) {
  // mish(x) = x*(t^2+2t)/(t^2+2t+2), t=e^x  (algebraic tanh(softplus))
  float t = __expf(x);
  float u = t * t + 2.f * t;
  float r = u / (u + 2.f);
  return (x > 30.f) ? x : x * r;
}

// ---------------- transpose + fp32->bf16 convert (dims multiples of 32) ----------------
__global__ __launch_bounds__(256) void k_transpose_cvt(const float* __restrict__ src,
                                                       ushort_t* __restrict__ dst, int R, int C) {
  __shared__ float tile[32][33];
  const int c0 = blockIdx.x * 32, r0 = blockIdx.y * 32;
  const int tc = threadIdx.x & 31, tr = threadIdx.x >> 5;
#pragma unroll
  for (int i = 0; i < 4; ++i) {
    const int r = tr + i * 8;
    tile[r][tc] = src[(size_t)(r0 + r) * C + (c0 + tc)];
  }
  __syncthreads();
#pragma unroll
  for (int i = 0; i < 4; ++i) {
    const int rr = tr + i * 8;
    dst[(size_t)(c0 + rr) * R + (r0 + tc)] = f2bf(tile[tc][rr]);
  }
}

// ---------------- key table fp32 -> bf16 ----------------
__global__ __launch_bounds__(256) void k_cvtkey(const float* __restrict__ src, ushort_t* __restrict__ dst) {
  const int i = blockIdx.x * 1024 + threadIdx.x;
#pragma unroll
  for (int j = 0; j < 4; ++j) dst[i + j * 256] = f2bf(src[i + j * 256]);
}

// ---------------- enc table: enc[v] = mish(v*cd_w1+cd_b1) @ cd_w2 + cd_b2 ----------------
// grid (65, 4): blockIdx.y picks a 256-col quarter. Per-column accumulation order unchanged.
__global__ __launch_bounds__(256) void k_enc(const float* __restrict__ w1, const float* __restrict__ b1,
                                             const float* __restrict__ w2, const float* __restrict__ b2,
                                             float* __restrict__ enc) {
  const int v = blockIdx.x, t = threadIdx.x;
  const int c = blockIdx.y * 256 + t;
  __shared__ float m[MIDCD];
  for (int i = t; i < MIDCD; i += 256) {
    double a = (double)v * (double)w1[i] + (double)b1[i];
    m[i] = (float)mish_d(a);
  }
  __syncthreads();
  double s = (double)b2[c];
  for (int k = 0; k < MIDCD; ++k) s += (double)m[k] * (double)w2[(size_t)k * H_SZ + c];
  enc[(size_t)v * H_SZ + c] = (float)s;
}

// ---------------- n-path: 4 rows per block (grid 512 -> 2 blocks/CU for TLP) ----------------
// fp32 S accumulation, fp64 LN/mish/dot. Per-row numerics identical to the 8-row version.
__global__ __launch_bounds__(256) void k_npath(
    const float* __restrict__ z, const float* __restrict__ w1, const float* __restrict__ b1,
    const float* __restrict__ g, const float* __restrict__ be,
    const float* __restrict__ w2, const float* __restrict__ b2,
    const float* __restrict__ enc, int* __restrict__ nbuf,
    ushort_t* __restrict__ zc, float* __restrict__ outb) {
  const int t = threadIdx.x;
  const int r0 = blockIdx.x * 4;
  const int lane = t & 63, wv = t >> 6;
  __shared__ float zs[4][H_SZ];      // 16 KB
  __shared__ double wred[4];
  __shared__ int n4[4];

#pragma unroll
  for (int i = 0; i < 16; ++i) {
    const int idx = i * 256 + t;
    zs[idx >> 10][idx & 1023] = z[(size_t)r0 * H_SZ + idx];
  }
  __syncthreads();

  const int c0 = t, c1 = t + 256;
  float a0[4], a1[4];
#pragma unroll
  for (int r = 0; r < 4; ++r) { a0[r] = 0.f; a1[r] = 0.f; }

  for (int k = 0; k < H_SZ; k += 4) {
    float4 zr[4];
#pragma unroll
    for (int r = 0; r < 4; ++r) zr[r] = *(const float4*)&zs[r][k];
#pragma unroll
    for (int kk = 0; kk < 4; ++kk) {
      const float w0 = w1[(size_t)(k + kk) * MIDSP + c0];
      const float w1v = w1[(size_t)(k + kk) * MIDSP + c1];
#pragma unroll
      for (int r = 0; r < 4; ++r) {
        const float zk = ((const float*)&zr[r])[kk];
        a0[r] += zk * w0;
        a1[r] += zk * w1v;
      }
    }
  }

  auto block_sum = [&](double v) -> double {
#pragma unroll
    for (int off = 32; off > 0; off >>= 1) v += __shfl_down(v, off, 64);
    if (lane == 0) wred[wv] = v;
    __syncthreads();
    const double s = wred[0] + wred[1] + wred[2] + wred[3];
    __syncthreads();
    return s;
  };

  const double bia0 = (double)b1[c0], bia1 = (double)b1[c1];
  const double g0 = (double)g[c0], g1 = (double)g[c1];
  const double be0 = (double)be[c0], be1 = (double)be[c1];
  const double wv0 = (double)w2[c0], wv1 = (double)w2[c1];
  const double b2v = (double)b2[0];

  for (int r = 0; r < 4; ++r) {
    const double x0 = (double)a0[r] + bia0;
    const double x1 = (double)a1[r] + bia1;
    const double mu = block_sum(x0 + x1) * (1.0 / 512.0);
    const double varr = block_sum((x0 - mu) * (x0 - mu) + (x1 - mu) * (x1 - mu)) * (1.0 / 512.0);
    const double rs = 1.0 / sqrt(varr + 1e-5);
    const double h0 = mish_d((x0 - mu) * rs * g0 + be0);
    const double h1 = mish_d((x1 - mu) * rs * g1 + be1);
    const double logit = block_sum(h0 * wv0 + h1 * wv1) + b2v;
    if (t == 0) n4[r] = (int)fmin(64.0, fmax(0.0, rint(logit)));  // rint = half-to-even = np.round
  }
  __syncthreads();

  if (t < 4) nbuf[r0 + t] = n4[t];
  {
    const int r = t >> 6, j = t & 63;    // 256 = 4 rows x 64 cols
    outb[(size_t)(r0 + r) * MAXN + j] = (j < n4[r]) ? (float)(r0 + r) : -1.0f;
  }
#pragma unroll
  for (int i = 0; i < 16; ++i) {
    const int idx = i * 256 + t;
    const int r = idx >> 10, c = idx & 1023;
    zc[(size_t)(r0 + r) * H_SZ + c] = f2bf(zs[r][c] - enc[(size_t)n4[r] * H_SZ + c]);
  }
}

// ---------------- fused decoder v9: the <=128-total-reg / 72KiB-LDS box -------------------
// R7 post-mortem: occupancy is governed by UNIFIED VGPR+AGPR total (CSV VGPR_Count
// excludes AGPRs). Retrodiction: v2 116+96=212, v6 100+96=196, v8 120+48=168 -> all
// >128 -> 2 waves/SIMD -> 1 block/CU (meas. 20-24% every round). 4 waves/SIMD (2 blocks
// x 8 waves) needs total <=128 (m69: waves halve at 64/128/256).
// v9 engineering: acc = acc2[2][4](32) + acc[2](8) = 40 via 6 passes x 128 cols;
// X-epilogue = DIRECT global stores (64B-contiguous per 16-lane group; same rnbf
// rounding -> bitwise-identical output), removing sT round-trip + 8 barriers;
// sT = 8 KiB -> LDS 72 KiB x 2 = 144 <= 160 (slack). Only MT=2 code path exists
// (garbage tiles masked at store: MFMA row m depends only on A row m). K-order in both
// GEMMs identical to v8 -> numerics inherited. launch_bounds(512,4) enforces the cap;
// spill detector = FETCH_SIZE (ideal ~80 MB; ballooning means the box failed).
static __device__ __forceinline__ void dec_sweep2(
    char* sA, char* sT,
    const ushort_t* __restrict__ w1t, const float* __restrict__ db1,
    const ushort_t* __restrict__ w2t, const float* __restrict__ db2,
    float* __restrict__ ob, const int tid, const int lim) {  // ob -> row r0 of this b
  const int lane = tid & 63;
  const int w = tid >> 6;           // 8 waves
  const int q = lane >> 4;
  const int l15 = lane & 15;
  const int x7 = l15 & 7;

  f32x4 z4 = {0.f, 0.f, 0.f, 0.f};
  f32x4 acc2[2][4];                 // X accumulator, persists across passes (32 regs)
#pragma unroll
  for (int mt = 0; mt < 2; ++mt)
#pragma unroll
    for (int i = 0; i < 4; ++i) acc2[mt][i] = z4;

  for (int p = 0; p < 6; ++p) {
    // ---- GEMM1 slab: T[:, p*128 .. p*128+128), barrier-free over K=1024 ----
    f32x4 acc0 = z4, acc1 = z4;     // one 16-col tile per wave (8 regs)
    const ushort_t* bp1 = w1t + (size_t)(p * 128 + w * 16 + l15) * H_SZ + q * 8;
    const char* sa0 = sA + (size_t)l15 * 2048;

#pragma unroll 4
    for (int ks = 0; ks < 32; ++ks) {      // k = ks*32, same order as v2..v8
      bf16x8 bfr = *(const bf16x8*)(bp1 + ks * 32);
      bf16x8 a0 = *(const bf16x8*)(sa0 + (((ks * 4 + q) ^ x7) * 16));
      bf16x8 a1 = *(const bf16x8*)(sa0 + 16 * 2048 + (((ks * 4 + q) ^ x7) * 16));
      acc0 = __builtin_amdgcn_mfma_f32_16x16x32_bf16(a0, bfr, acc0, 0, 0, 0);
      acc1 = __builtin_amdgcn_mfma_f32_16x16x32_bf16(a1, bfr, acc1, 0, 0, 0);
    }

    // ---- epilogue1: +bias, mish, bf16 -> sT[32][128] (XOR-swizzled 16B chunks) ----
    {
      const int pl = w * 16 + l15;          // local col 0..127
      const float bias = db1[p * 128 + pl];
      const int c = pl >> 3;                // chunk 0..15
      const int off = (pl & 7) * 2;
#pragma unroll
      for (int r = 0; r < 4; ++r) {
        const int j0 = q * 4 + r;
        *(ushort_t*)(sT + j0 * 256 + ((c ^ (j0 & 7)) * 16 + off)) = f2bf(mish_f(acc0[r] + bias));
        const int j1 = 16 + q * 4 + r;
        *(ushort_t*)(sT + j1 * 256 + ((c ^ (j1 & 7)) * 16 + off)) = f2bf(mish_f(acc1[r] + bias));
      }
    }
    __syncthreads();

    // ---- GEMM2 partial: acc2 += T-slab(32x128) @ W2[p*128.., :] ----
    const ushort_t* bp2 = w2t + (size_t)(w * 64 + l15) * MIDDEC + p * 128 + q * 8;
    const char* st0 = sT + (size_t)l15 * 256;
#pragma unroll
    for (int ksl = 0; ksl < 4; ++ksl) {
      bf16x8 bfr[4];
#pragma unroll
      for (int i = 0; i < 4; ++i) bfr[i] = *(const bf16x8*)(bp2 + (size_t)i * 16 * MIDDEC + ksl * 32);
      bf16x8 a0 = *(const bf16x8*)(st0 + (((ksl * 4 + q) ^ x7) * 16));
      bf16x8 a1 = *(const bf16x8*)(st0 + 16 * 256 + (((ksl * 4 + q) ^ x7) * 16));
#pragma unroll
      for (int i = 0; i < 4; ++i) {
        acc2[0][i] = __builtin_amdgcn_mfma_f32_16x16x32_bf16(a0, bfr[i], acc2[0][i], 0, 0, 0);
        acc2[1][i] = __builtin_amdgcn_mfma_f32_16x16x32_bf16(a1, bfr[i], acc2[1][i], 0, 0, 0);
      }
    }
    __syncthreads();   // sT reads done before next pass's epilogue overwrites
  }

  // ---- X epilogue: DIRECT coalesced global stores (no LDS, no barriers) ----
  // lane group q writes rows q*4+r; 16 lanes -> 64B contiguous line per (mt,i,r).
#pragma unroll
  for (int mt = 0; mt < 2; ++mt)
#pragma unroll
    for (int i = 0; i < 4; ++i) {
      const int col = (w * 4 + i) * 16 + l15;   // 0..511
      const float bias = db2[col];
#pragma unroll
      for (int r = 0; r < 4; ++r) {
        const int j = mt * 16 + q * 4 + r;
        const float v = (j < lim) ? bf2f(acc2[mt][i][r] + bias) : 0.f;
        ob[(size_t)j * D_OUT + col] = v;
      }
    }
}

__global__ __launch_bounds__(512, 4) void k_dec(
    const ushort_t* __restrict__ key, const ushort_t* __restrict__ w1t,
    const float* __restrict__ db1, const ushort_t* __restrict__ w2t,
    const float* __restrict__ db2, const ushort_t* __restrict__ zc,
    const int* __restrict__ nbuf, float* __restrict__ out) {
  __shared__ char sA[65536];       // 32 rows x 1024 K bf16, row stride 2048B, XOR-16B-chunk swizzle
  __shared__ char sT[8192];        // 32 rows x 128 cols bf16, row stride 256B, XOR swizzle

  const int tid = threadIdx.x;
  const int b = blockIdx.x;

  int n = nbuf[b];
  n = n < 0 ? 0 : (n > MAXN ? MAXN : n);   // defensive clamp
  float* ob = out + (size_t)b * (MAXN * D_OUT);

  if (n == 0) {                     // dead b: zero-fill 64x512 fp32 and exit (uniform)
    const float4 z4f = make_float4(0.f, 0.f, 0.f, 0.f);
#pragma unroll
    for (int i = 0; i < 16; ++i) *(float4*)(ob + i * 2048 + tid * 4) = z4f;
    return;
  }

  // ---- A-gen indexing: row gj = tid>>4 (0..31), 8 x 16B chunks per thread ----
  const int gj = tid >> 4;
  const int gk = tid & 15;
  const ushort_t* zrow = zc + (size_t)b * H_SZ + gk * 8;
  char* awbase = sA + gj * 2048;
  const int xj = gj & 7;

  // ---- sweep 0: rows 0..31 (always; tiles beyond n are masked at store) ----
  {
    const ushort_t* keyrow = key + (size_t)gj * H_SZ + gk * 8;
#pragma unroll
    for (int i = 0; i < 8; ++i) {
      const int c = i * 16 + gk;    // chunk index 0..127 (XOR touches low 3 bits only)
      uint4 kv = *(const uint4*)(keyrow + i * 128);
      uint4 zv = *(const uint4*)(zrow + i * 128);
      uint4 r;
      r.x = mul2bf(kv.x, zv.x); r.y = mul2bf(kv.y, zv.y);
      r.z = mul2bf(kv.z, zv.z); r.w = mul2bf(kv.w, zv.w);
      *(uint4*)(awbase + ((c ^ xj) * 16)) = r;
    }
  }
  __syncthreads();
  {
    const int lim = n > 32 ? 32 : n;
    dec_sweep2(sA, sT, w1t, db1, w2t, db2, ob, tid, lim);
  }

  if (n > 32) {                     // rare: rows 32..63 live -> second sweep
    __syncthreads();                // all sA/sT reads of sweep 0 complete
    const ushort_t* keyrow = key + (size_t)(32 + gj) * H_SZ + gk * 8;
#pragma unroll
    for (int i = 0; i < 8; ++i) {
      const int c = i * 16 + gk;
      uint4 kv = *(const uint4*)(keyrow + i * 128);
      uint4 zv = *(const uint4*)(zrow + i * 128);
      uint4 r;
      r.x = mul2bf(kv.x, zv.x); r.y = mul2bf(kv.y, zv.y);
      r.z = mul2bf(kv.z, zv.z); r.w = mul2bf(kv.w, zv.w);
      *(uint4*)(awbase + ((c ^ xj) * 16)) = r;
    }
    __syncthreads();
    dec_sweep2(sA, sT, w1t, db1, w2t, db2, ob + (size_t)32 * D_OUT, tid, n - 32);
  } else {                          // rows 32..63 dead: zero-fill 32x512 fp32
    float* oz = ob + 32 * D_OUT;
    const float4 z4f = make_float4(0.f, 0.f, 0.f, 0.f);
#pragma unroll
    for (int i = 0; i < 8; ++i) *(float4*)(oz + i * 2048 + tid * 4) = z4f;
  }
}

// ---------------- launcher ----------------
extern "C" void kernel_launch(void* const* d_in, const int* in_sizes, int n_in,
                              void* d_out, int out_size, void* d_ws, size_t ws_size,
                              hipStream_t stream) {
  const float* z      = (const float*)d_in[0];
  const float* key    = (const float*)d_in[1];
  const float* sp_w1  = (const float*)d_in[2];
  const float* sp_b1  = (const float*)d_in[3];
  const float* sp_g   = (const float*)d_in[4];
  const float* sp_be  = (const float*)d_in[5];
  const float* sp_w2  = (const float*)d_in[6];
  const float* sp_b2  = (const float*)d_in[7];
  const float* cd_w1  = (const float*)d_in[8];
  const float* cd_b1  = (const float*)d_in[9];
  const float* cd_w2  = (const float*)d_in[10];
  const float* cd_b2  = (const float*)d_in[11];
  const float* dec_w1 = (const float*)d_in[12];
  const float* dec_b1 = (const float*)d_in[13];
  const float* dec_w2 = (const float*)d_in[14];
  const float* dec_b2 = (const float*)d_in[15];

  char* ws = (char*)d_ws;
  float*    enc   = (float*)(ws + 0);           // 65*1024*4   = 266,240
  int*      nbuf  = (int*)(ws + 266240);        // 2048*4      = 8,192
  ushort_t* zc    = (ushort_t*)(ws + 274432);   // 2048*1024*2 = 4,194,304
  ushort_t* w1t   = (ushort_t*)(ws + 4468736);  // 768*1024*2  = 1,572,864
  ushort_t* w2t   = (ushort_t*)(ws + 6041600);  // 512*768*2   = 786,432
  ushort_t* keyb  = (ushort_t*)(ws + 6828032);  // 64*1024*2   = 131,072

  float* out  = (float*)d_out;                           // x: 2048*64*512 fp32
  float* outb = out + (size_t)2048 * MAXN * D_OUT;       // batch: 2048*64 fp32

  (void)in_sizes; (void)n_in; (void)out_size; (void)ws_size;

  k_transpose_cvt<<<dim3(768 / 32, 1024 / 32), 256, 0, stream>>>(dec_w1, w1t, 1024, 768);
  k_transpose_cvt<<<dim3(512 / 32, 768 / 32), 256, 0, stream>>>(dec_w2, w2t, 768, 512);
  k_cvtkey<<<64, 256, 0, stream>>>(key, keyb);
  k_enc<<<dim3(65, 4), 256, 0, stream>>>(cd_w1, cd_b1, cd_w2, cd_b2, enc);
  k_npath<<<512, 256, 0, stream>>>(z, sp_w1, sp_b1, sp_g, sp_be, sp_w2, sp_b2, enc, nbuf, zc, outb);
  k_dec<<<2048, 512, 0, stream>>>(keyb, w1t, dec_b1, w2t, dec_b2, zc, nbuf, out);
}

// Round 9
// 731.641 us; speedup vs baseline: 1.6319x; 1.4722x over previous
//
#include <hip/hip_runtime.h>
#include <stdint.h>

typedef unsigned short ushort_t;
typedef unsigned int uint_t;

#define H_SZ   1024
#define D_OUT  512
#define MAXN   64
#define MIDSP  512
#define MIDCD  512
#define MIDDEC 768

typedef __bf16 bf16x8 __attribute__((ext_vector_type(8)));
typedef float  f32x4  __attribute__((ext_vector_type(4)));

static __device__ __forceinline__ float asf(uint_t u) { union { uint_t i; float f; } c; c.i = u; return c.f; }
static __device__ __forceinline__ uint_t rnbf(float f) {            // fp32 -> bf16 (RNE), low 16 bits
  union { uint_t i; float f; } c; c.f = f;
  return (c.i + 0x7fffu + ((c.i >> 16) & 1u)) >> 16;
}
static __device__ __forceinline__ ushort_t f2bf(float f) { return (ushort_t)rnbf(f); }
static __device__ __forceinline__ float bf2f(float f) { return asf(rnbf(f) << 16); }  // round to bf16, keep fp32
static __device__ __forceinline__ uint_t mul2bf(uint_t a, uint_t b) {  // 2x packed bf16 multiply
  float a0 = asf(a << 16), a1 = asf(a & 0xffff0000u);
  float b0 = asf(b << 16), b1 = asf(b & 0xffff0000u);
  return rnbf(a0 * b0) | (rnbf(a1 * b1) << 16);
}
static __device__ __forceinline__ double mish_d(double x) { return x * tanh(log1p(exp(x))); }
static __device__ __forceinline__ float mish_f(float x) {
  // mish(x) = x*(t^2+2t)/(t^2+2t+2), t=e^x  (algebraic tanh(softplus))
  float t = __expf(x);
  float u = t * t + 2.f * t;
  float r = u / (u + 2.f);
  return (x > 30.f) ? x : x * r;
}

// ---------------- pack W1 (fp32 [1024 k][768 mid]) -> MFMA-fragment order bf16 ------------
// pk1[w][p][ks][lane][8] : value = W1[k = ks*32 + q*8 + e][row = p*128 + w*16 + l15]
// (same bf16 values the old transpose+load path produced -> bitwise-identical GEMM input).
// A wave's B-load in k_dec becomes lane*16B consecutive = 1KB contiguous per instruction.
__global__ __launch_bounds__(256) void k_pack1(const float* __restrict__ w1,
                                               ushort_t* __restrict__ pk1) {
  const int t8 = blockIdx.x * 256 + threadIdx.x;   // 98304 fragments of 8 elements
  const int lane = t8 & 63;
  const int ks = (t8 >> 6) & 31;
  const int wp = t8 >> 11;                          // 0..47
  const int w = wp / 6, p = wp % 6;
  const int q = lane >> 4, l15 = lane & 15;
  const int row = p * 128 + w * 16 + l15;
  const int colb = ks * 32 + q * 8;
  ushort_t v[8];
#pragma unroll
  for (int e = 0; e < 8; ++e) v[e] = f2bf(w1[(size_t)(colb + e) * 768 + row]);
  *(uint4*)(pk1 + (size_t)t8 * 8) = *(const uint4*)v;
}

// ---------------- pack W2 (fp32 [768 k][512 n]) -> MFMA-fragment order bf16 ---------------
// pk2[w][p][ksl][i][lane][8] : value = W2[k = p*128 + ksl*32 + q*8 + e][row = w*64 + i*16 + l15]
__global__ __launch_bounds__(256) void k_pack2(const float* __restrict__ w2,
                                               ushort_t* __restrict__ pk2) {
  const int t8 = blockIdx.x * 256 + threadIdx.x;   // 49152 fragments of 8 elements
  const int lane = t8 & 63;
  const int ki = (t8 >> 6) & 15;                    // ksl*4 + i
  const int wp = t8 >> 10;                          // 0..47
  const int w = wp / 6, p = wp % 6;
  const int ksl = ki >> 2, i = ki & 3;
  const int q = lane >> 4, l15 = lane & 15;
  const int row = w * 64 + i * 16 + l15;
  const int colb = p * 128 + ksl * 32 + q * 8;
  ushort_t v[8];
#pragma unroll
  for (int e = 0; e < 8; ++e) v[e] = f2bf(w2[(size_t)(colb + e) * 512 + row]);
  *(uint4*)(pk2 + (size_t)t8 * 8) = *(const uint4*)v;
}

// ---------------- key table fp32 -> bf16 ----------------
__global__ __launch_bounds__(256) void k_cvtkey(const float* __restrict__ src, ushort_t* __restrict__ dst) {
  const int i = blockIdx.x * 1024 + threadIdx.x;
#pragma unroll
  for (int j = 0; j < 4; ++j) dst[i + j * 256] = f2bf(src[i + j * 256]);
}

// ---------------- enc table: enc[v] = mish(v*cd_w1+cd_b1) @ cd_w2 + cd_b2 ----------------
// grid (65, 4): blockIdx.y picks a 256-col quarter. Per-column accumulation order unchanged.
__global__ __launch_bounds__(256) void k_enc(const float* __restrict__ w1, const float* __restrict__ b1,
                                             const float* __restrict__ w2, const float* __restrict__ b2,
                                             float* __restrict__ enc) {
  const int v = blockIdx.x, t = threadIdx.x;
  const int c = blockIdx.y * 256 + t;
  __shared__ float m[MIDCD];
  for (int i = t; i < MIDCD; i += 256) {
    double a = (double)v * (double)w1[i] + (double)b1[i];
    m[i] = (float)mish_d(a);
  }
  __syncthreads();
  double s = (double)b2[c];
  for (int k = 0; k < MIDCD; ++k) s += (double)m[k] * (double)w2[(size_t)k * H_SZ + c];
  enc[(size_t)v * H_SZ + c] = (float)s;
}

// ---------------- n-path: 4 rows per block (grid 512 -> 2 blocks/CU for TLP) ----------------
// fp32 S accumulation, fp64 LN/mish/dot. Per-row numerics identical to the 8-row version.
__global__ __launch_bounds__(256) void k_npath(
    const float* __restrict__ z, const float* __restrict__ w1, const float* __restrict__ b1,
    const float* __restrict__ g, const float* __restrict__ be,
    const float* __restrict__ w2, const float* __restrict__ b2,
    const float* __restrict__ enc, int* __restrict__ nbuf,
    ushort_t* __restrict__ zc, float* __restrict__ outb) {
  const int t = threadIdx.x;
  const int r0 = blockIdx.x * 4;
  const int lane = t & 63, wv = t >> 6;
  __shared__ float zs[4][H_SZ];      // 16 KB
  __shared__ double wred[4];
  __shared__ int n4[4];

#pragma unroll
  for (int i = 0; i < 16; ++i) {
    const int idx = i * 256 + t;
    zs[idx >> 10][idx & 1023] = z[(size_t)r0 * H_SZ + idx];
  }
  __syncthreads();

  const int c0 = t, c1 = t + 256;
  float a0[4], a1[4];
#pragma unroll
  for (int r = 0; r < 4; ++r) { a0[r] = 0.f; a1[r] = 0.f; }

  for (int k = 0; k < H_SZ; k += 4) {
    float4 zr[4];
#pragma unroll
    for (int r = 0; r < 4; ++r) zr[r] = *(const float4*)&zs[r][k];
#pragma unroll
    for (int kk = 0; kk < 4; ++kk) {
      const float w0 = w1[(size_t)(k + kk) * MIDSP + c0];
      const float w1v = w1[(size_t)(k + kk) * MIDSP + c1];
#pragma unroll
      for (int r = 0; r < 4; ++r) {
        const float zk = ((const float*)&zr[r])[kk];
        a0[r] += zk * w0;
        a1[r] += zk * w1v;
      }
    }
  }

  auto block_sum = [&](double v) -> double {
#pragma unroll
    for (int off = 32; off > 0; off >>= 1) v += __shfl_down(v, off, 64);
    if (lane == 0) wred[wv] = v;
    __syncthreads();
    const double s = wred[0] + wred[1] + wred[2] + wred[3];
    __syncthreads();
    return s;
  };

  const double bia0 = (double)b1[c0], bia1 = (double)b1[c1];
  const double g0 = (double)g[c0], g1 = (double)g[c1];
  const double be0 = (double)be[c0], be1 = (double)be[c1];
  const double wv0 = (double)w2[c0], wv1 = (double)w2[c1];
  const double b2v = (double)b2[0];

  for (int r = 0; r < 4; ++r) {
    const double x0 = (double)a0[r] + bia0;
    const double x1 = (double)a1[r] + bia1;
    const double mu = block_sum(x0 + x1) * (1.0 / 512.0);
    const double varr = block_sum((x0 - mu) * (x0 - mu) + (x1 - mu) * (x1 - mu)) * (1.0 / 512.0);
    const double rs = 1.0 / sqrt(varr + 1e-5);
    const double h0 = mish_d((x0 - mu) * rs * g0 + be0);
    const double h1 = mish_d((x1 - mu) * rs * g1 + be1);
    const double logit = block_sum(h0 * wv0 + h1 * wv1) + b2v;
    if (t == 0) n4[r] = (int)fmin(64.0, fmax(0.0, rint(logit)));  // rint = half-to-even = np.round
  }
  __syncthreads();

  if (t < 4) nbuf[r0 + t] = n4[t];
  {
    const int r = t >> 6, j = t & 63;    // 256 = 4 rows x 64 cols
    outb[(size_t)(r0 + r) * MAXN + j] = (j < n4[r]) ? (float)(r0 + r) : -1.0f;
  }
#pragma unroll
  for (int i = 0; i < 16; ++i) {
    const int idx = i * 256 + t;
    const int r = idx >> 10, c = idx & 1023;
    zc[(size_t)(r0 + r) * H_SZ + c] = f2bf(zs[r][c] - enc[(size_t)n4[r] * H_SZ + c]);
  }
}

// ---------------- fused decoder v10: v9 + fragment-packed B operands ----------------------
// R8 post-mortem: 2 blocks/CU achieved (occ 37%, 104 unified regs) but time flat vs 1
// block/CU (687 vs 700) -> limiter is a SHARED per-CU throughput resource. MFMA/VALU/HBM/
// L2-bytes all <=20%; remaining suspect = VMEM request path: every B-load is wave64 over
// 16 SCATTERED 64B lines (row stride 2KB / 1.5KB) -> ~300K line-transactions per CU.
// v10: B pre-packed in MFMA-fragment order (k_pack1/k_pack2) so every B-load is 1KB
// CONTIGUOUS per instruction and each wave streams sequential 32KB runs. Same bf16 values,
// same order -> bitwise-identical output. LDS/regs/barriers/MFMA untouched (one variable).
static __device__ __forceinline__ void dec_sweep2(
    char* sA, char* sT,
    const ushort_t* __restrict__ pk1, const float* __restrict__ db1,
    const ushort_t* __restrict__ pk2, const float* __restrict__ db2,
    float* __restrict__ ob, const int tid, const int lim) {  // ob -> row r0 of this b
  const int lane = tid & 63;
  const int w = tid >> 6;           // 8 waves
  const int q = lane >> 4;
  const int l15 = lane & 15;
  const int x7 = l15 & 7;

  f32x4 z4 = {0.f, 0.f, 0.f, 0.f};
  f32x4 acc2[2][4];                 // X accumulator, persists across passes (32 regs)
#pragma unroll
  for (int mt = 0; mt < 2; ++mt)
#pragma unroll
    for (int i = 0; i < 4; ++i) acc2[mt][i] = z4;

  for (int p = 0; p < 6; ++p) {
    // ---- GEMM1 slab: T[:, p*128 .. p*128+128), barrier-free over K=1024 ----
    f32x4 acc0 = z4, acc1 = z4;     // one 16-col tile per wave (8 regs)
    const ushort_t* bp1 = pk1 + ((size_t)(w * 6 + p) << 14) + lane * 8;  // 16384 el per (w,p)
    const char* sa0 = sA + (size_t)l15 * 2048;

#pragma unroll 4
    for (int ks = 0; ks < 32; ++ks) {      // k = ks*32, same order as v2..v9
      bf16x8 bfr = *(const bf16x8*)(bp1 + ks * 512);   // 1KB contiguous per wave
      bf16x8 a0 = *(const bf16x8*)(sa0 + (((ks * 4 + q) ^ x7) * 16));
      bf16x8 a1 = *(const bf16x8*)(sa0 + 16 * 2048 + (((ks * 4 + q) ^ x7) * 16));
      acc0 = __builtin_amdgcn_mfma_f32_16x16x32_bf16(a0, bfr, acc0, 0, 0, 0);
      acc1 = __builtin_amdgcn_mfma_f32_16x16x32_bf16(a1, bfr, acc1, 0, 0, 0);
    }

    // ---- epilogue1: +bias, mish, bf16 -> sT[32][128] (XOR-swizzled 16B chunks) ----
    {
      const int pl = w * 16 + l15;          // local col 0..127
      const float bias = db1[p * 128 + pl];
      const int c = pl >> 3;                // chunk 0..15
      const int off = (pl & 7) * 2;
#pragma unroll
      for (int r = 0; r < 4; ++r) {
        const int j0 = q * 4 + r;
        *(ushort_t*)(sT + j0 * 256 + ((c ^ (j0 & 7)) * 16 + off)) = f2bf(mish_f(acc0[r] + bias));
        const int j1 = 16 + q * 4 + r;
        *(ushort_t*)(sT + j1 * 256 + ((c ^ (j1 & 7)) * 16 + off)) = f2bf(mish_f(acc1[r] + bias));
      }
    }
    __syncthreads();

    // ---- GEMM2 partial: acc2 += T-slab(32x128) @ W2[p*128.., :] ----
    const ushort_t* bp2 = pk2 + ((size_t)(w * 6 + p) << 13) + lane * 8;  // 8192 el per (w,p)
    const char* st0 = sT + (size_t)l15 * 256;
#pragma unroll
    for (int ksl = 0; ksl < 4; ++ksl) {
      bf16x8 bfr[4];
#pragma unroll
      for (int i = 0; i < 4; ++i) bfr[i] = *(const bf16x8*)(bp2 + (ksl * 4 + i) * 512);
      bf16x8 a0 = *(const bf16x8*)(st0 + (((ksl * 4 + q) ^ x7) * 16));
      bf16x8 a1 = *(const bf16x8*)(st0 + 16 * 256 + (((ksl * 4 + q) ^ x7) * 16));
#pragma unroll
      for (int i = 0; i < 4; ++i) {
        acc2[0][i] = __builtin_amdgcn_mfma_f32_16x16x32_bf16(a0, bfr[i], acc2[0][i], 0, 0, 0);
        acc2[1][i] = __builtin_amdgcn_mfma_f32_16x16x32_bf16(a1, bfr[i], acc2[1][i], 0, 0, 0);
      }
    }
    __syncthreads();   // sT reads done before next pass's epilogue overwrites
  }

  // ---- X epilogue: DIRECT coalesced global stores (no LDS, no barriers) ----
  // lane group q writes rows q*4+r; 16 lanes -> 64B contiguous line per (mt,i,r).
#pragma unroll
  for (int mt = 0; mt < 2; ++mt)
#pragma unroll
    for (int i = 0; i < 4; ++i) {
      const int col = (w * 4 + i) * 16 + l15;   // 0..511
      const float bias = db2[col];
#pragma unroll
      for (int r = 0; r < 4; ++r) {
        const int j = mt * 16 + q * 4 + r;
        const float v = (j < lim) ? bf2f(acc2[mt][i][r] + bias) : 0.f;
        ob[(size_t)j * D_OUT + col] = v;
      }
    }
}

__global__ __launch_bounds__(512, 4) void k_dec(
    const ushort_t* __restrict__ key, const ushort_t* __restrict__ pk1,
    const float* __restrict__ db1, const ushort_t* __restrict__ pk2,
    const float* __restrict__ db2, const ushort_t* __restrict__ zc,
    const int* __restrict__ nbuf, float* __restrict__ out) {
  __shared__ char sA[65536];       // 32 rows x 1024 K bf16, row stride 2048B, XOR-16B-chunk swizzle
  __shared__ char sT[8192];        // 32 rows x 128 cols bf16, row stride 256B, XOR swizzle

  const int tid = threadIdx.x;
  const int b = blockIdx.x;

  int n = nbuf[b];
  n = n < 0 ? 0 : (n > MAXN ? MAXN : n);   // defensive clamp
  float* ob = out + (size_t)b * (MAXN * D_OUT);

  if (n == 0) {                     // dead b: zero-fill 64x512 fp32 and exit (uniform)
    const float4 z4f = make_float4(0.f, 0.f, 0.f, 0.f);
#pragma unroll
    for (int i = 0; i < 16; ++i) *(float4*)(ob + i * 2048 + tid * 4) = z4f;
    return;
  }

  // ---- A-gen indexing: row gj = tid>>4 (0..31), 8 x 16B chunks per thread ----
  const int gj = tid >> 4;
  const int gk = tid & 15;
  const ushort_t* zrow = zc + (size_t)b * H_SZ + gk * 8;
  char* awbase = sA + gj * 2048;
  const int xj = gj & 7;

  // ---- sweep 0: rows 0..31 (always; tiles beyond n are masked at store) ----
  {
    const ushort_t* keyrow = key + (size_t)gj * H_SZ + gk * 8;
#pragma unroll
    for (int i = 0; i < 8; ++i) {
      const int c = i * 16 + gk;    // chunk index 0..127 (XOR touches low 3 bits only)
      uint4 kv = *(const uint4*)(keyrow + i * 128);
      uint4 zv = *(const uint4*)(zrow + i * 128);
      uint4 r;
      r.x = mul2bf(kv.x, zv.x); r.y = mul2bf(kv.y, zv.y);
      r.z = mul2bf(kv.z, zv.z); r.w = mul2bf(kv.w, zv.w);
      *(uint4*)(awbase + ((c ^ xj) * 16)) = r;
    }
  }
  __syncthreads();
  {
    const int lim = n > 32 ? 32 : n;
    dec_sweep2(sA, sT, pk1, db1, pk2, db2, ob, tid, lim);
  }

  if (n > 32) {                     // rare: rows 32..63 live -> second sweep
    __syncthreads();                // all sA/sT reads of sweep 0 complete
    const ushort_t* keyrow = key + (size_t)(32 + gj) * H_SZ + gk * 8;
#pragma unroll
    for (int i = 0; i < 8; ++i) {
      const int c = i * 16 + gk;
      uint4 kv = *(const uint4*)(keyrow + i * 128);
      uint4 zv = *(const uint4*)(zrow + i * 128);
      uint4 r;
      r.x = mul2bf(kv.x, zv.x); r.y = mul2bf(kv.y, zv.y);
      r.z = mul2bf(kv.z, zv.z); r.w = mul2bf(kv.w, zv.w);
      *(uint4*)(awbase + ((c ^ xj) * 16)) = r;
    }
    __syncthreads();
    dec_sweep2(sA, sT, pk1, db1, pk2, db2, ob + (size_t)32 * D_OUT, tid, n - 32);
  } else {                          // rows 32..63 dead: zero-fill 32x512 fp32
    float* oz = ob + 32 * D_OUT;
    const float4 z4f = make_float4(0.f, 0.f, 0.f, 0.f);
#pragma unroll
    for (int i = 0; i < 8; ++i) *(float4*)(oz + i * 2048 + tid * 4) = z4f;
  }
}

// ---------------- launcher ----------------
extern "C" void kernel_launch(void* const* d_in, const int* in_sizes, int n_in,
                              void* d_out, int out_size, void* d_ws, size_t ws_size,
                              hipStream_t stream) {
  const float* z      = (const float*)d_in[0];
  const float* key    = (const float*)d_in[1];
  const float* sp_w1  = (const float*)d_in[2];
  const float* sp_b1  = (const float*)d_in[3];
  const float* sp_g   = (const float*)d_in[4];
  const float* sp_be  = (const float*)d_in[5];
  const float* sp_w2  = (const float*)d_in[6];
  const float* sp_b2  = (const float*)d_in[7];
  const float* cd_w1  = (const float*)d_in[8];
  const float* cd_b1  = (const float*)d_in[9];
  const float* cd_w2  = (const float*)d_in[10];
  const float* cd_b2  = (const float*)d_in[11];
  const float* dec_w1 = (const float*)d_in[12];
  const float* dec_b1 = (const float*)d_in[13];
  const float* dec_w2 = (const float*)d_in[14];
  const float* dec_b2 = (const float*)d_in[15];

  char* ws = (char*)d_ws;
  float*    enc   = (float*)(ws + 0);           // 65*1024*4   = 266,240
  int*      nbuf  = (int*)(ws + 266240);        // 2048*4      = 8,192
  ushort_t* zc    = (ushort_t*)(ws + 274432);   // 2048*1024*2 = 4,194,304
  ushort_t* pk1   = (ushort_t*)(ws + 4468736);  // 768*1024*2  = 1,572,864 (packed W1)
  ushort_t* pk2   = (ushort_t*)(ws + 6041600);  // 512*768*2   = 786,432   (packed W2)
  ushort_t* keyb  = (ushort_t*)(ws + 6828032);  // 64*1024*2   = 131,072

  float* out  = (float*)d_out;                           // x: 2048*64*512 fp32
  float* outb = out + (size_t)2048 * MAXN * D_OUT;       // batch: 2048*64 fp32

  (void)in_sizes; (void)n_in; (void)out_size; (void)ws_size;

  k_pack1<<<384, 256, 0, stream>>>(dec_w1, pk1);
  k_pack2<<<192, 256, 0, stream>>>(dec_w2, pk2);
  k_cvtkey<<<64, 256, 0, stream>>>(key, keyb);
  k_enc<<<dim3(65, 4), 256, 0, stream>>>(cd_w1, cd_b1, cd_w2, cd_b2, enc);
  k_npath<<<512, 256, 0, stream>>>(z, sp_w1, sp_b1, sp_g, sp_be, sp_w2, sp_b2, enc, nbuf, zc, outb);
  k_dec<<<2048, 512, 0, stream>>>(keyb, pk1, dec_b1, pk2, dec_b2, zc, nbuf, out);
}